// Round 7
// baseline (434.660 us; speedup 1.0000x reference)
//
#include <hip/hip_runtime.h>
#include <cmath>

// AdaAttnNoConv: b=4, C=512, hw=4096 (fp32 in/out).
// Round 7: non-pv polish. k_pv untouched (at the 874 TF m97 plateau).
//  - k_qk: (m_t,l_t) at 128-col granularity -> wave-local, sred removed,
//    single-phase E transpose through full 128-row ebuf: 2 epilogue barriers.
//  - k_stats: wave-per-channel, shuffle-only (no LDS/barriers).
//  - prept x2 merged into one launch.
//   k_qk : S-tile GEMM, epilogue stores E = exp(s - m_tile) f16 + (m_t, l_t)
//   k_red: exact softmax merge -> alpha[row][kt32] = exp(m_t - m)/l  (f32)
//   k_pv : (E*alpha) x V GEMM, M=A.V, M2=A.V^2 (in-reg square),
//          fused sqrt(clip(M2-M^2))*IN(c_x)+M epilogue. XCD-clustered.

#define B_  4
#define C_  512
#define HW_ 4096

typedef _Float16 f16;
typedef _Float16 f16x8 __attribute__((ext_vector_type(8)));
typedef float    f32x4 __attribute__((ext_vector_type(4)));

// Verified gfx950 fragment layouts (learn_hip m89/m91, rounds 1-6 passed):
//  A[m][k]: m = lane&15, k = quad*8 + j
//  B[k][n]: n = lane&15, k = quad*8 + j
//  C/D[m][n]: n = lane&15, m = quad*4 + reg
__device__ __forceinline__ f32x4 mfma16(f16x8 a, f16x8 b, f32x4 c) {
  return __builtin_amdgcn_mfma_f32_16x16x32_f16(a, b, c, 0, 0, 0);
}
__device__ __forceinline__ void g2l16(const f16* g, f16* l) {
  __builtin_amdgcn_global_load_lds(
      (const __attribute__((address_space(1))) void*)g,
      (__attribute__((address_space(3))) void*)l, 16, 0, 0);
}

// ---------------- pass 0: instance-norm stats (mean, rstd) ----------------
// wave-per-channel: 64-lane shuffle reduce, no LDS, no barriers.
__global__ __launch_bounds__(256) void k_stats(
    const float* __restrict__ cx, const float* __restrict__ c1,
    const float* __restrict__ s1,
    float2* __restrict__ cxs, float2* __restrict__ c1s, float2* __restrict__ s1s) {
  int wave = threadIdx.x >> 6, lane = threadIdx.x & 63;
  int c = blockIdx.x * 4 + wave, b = blockIdx.y, t = blockIdx.z;
  const float* src = (t == 0 ? cx : (t == 1 ? c1 : s1)) + (size_t)(b * C_ + c) * HW_;
  const float4* src4 = (const float4*)src;
  float s = 0.f, q = 0.f;
#pragma unroll
  for (int j = 0; j < 16; ++j) {
    float4 v = src4[lane + j * 64];
    s += v.x + v.y + v.z + v.w;
    q += v.x * v.x + v.y * v.y + v.z * v.z + v.w * v.w;
  }
#pragma unroll
  for (int off = 1; off < 64; off <<= 1) {
    s += __shfl_xor(s, off);
    q += __shfl_xor(q, off);
  }
  if (lane == 0) {
    float mean = s * (1.f / HW_);
    float var = q * (1.f / HW_) - mean * mean;
    float2 r;
    r.x = mean;
    r.y = rsqrtf(var + 1e-5f);
    (t == 0 ? cxs : (t == 1 ? c1s : s1s))[b * C_ + c] = r;
  }
}

// -- pass 1: normalize + transpose (b,c,p) f32 -> (b,p,c) f16, both tensors --
__global__ __launch_bounds__(256) void k_prept(
    const float* __restrict__ c1x, const float* __restrict__ s1x,
    const float2* __restrict__ c1s, const float2* __restrict__ s1s,
    f16* __restrict__ Qt, f16* __restrict__ Kt) {
  int pb = blockIdx.x * 64, cb = blockIdx.y * 64;
  int b = blockIdx.z >> 1, which = blockIdx.z & 1;
  const float* src = which ? s1x : c1x;
  const float2* st = which ? s1s : c1s;
  f16* dst = which ? Kt : Qt;
  __shared__ float t[64][65];
  int tj = threadIdx.x & 63, tr = threadIdx.x >> 6;
#pragma unroll 4
  for (int p = 0; p < 16; ++p) {
    int cl = p * 4 + tr;
    float2 mr = st[b * C_ + cb + cl];
    float v = src[(size_t)(b * C_ + cb + cl) * HW_ + pb + tj];
    t[cl][tj] = (v - mr.x) * mr.y;
  }
  __syncthreads();
#pragma unroll 4
  for (int p = 0; p < 16; ++p) {
    int pr = p * 4 + tr;
    dst[(size_t)(b * HW_ + pb + pr) * C_ + cb + tj] = (f16)t[tj][pr];
  }
}

// ---------------- pass 1b: V = s_x -> f16 (same [b][c][k] layout) ---------
__global__ __launch_bounds__(256) void k_prepv(const float* __restrict__ src,
                                               f16* __restrict__ dst) {
  int gid = blockIdx.x * 256 + threadIdx.x;  // over B_*C_*HW_/8
  const float4* s = (const float4*)src + (size_t)gid * 2;
  float4 v0 = s[0], v1 = s[1];
  f16x8 v = {(f16)v0.x, (f16)v0.y, (f16)v0.z, (f16)v0.w,
             (f16)v1.x, (f16)v1.y, (f16)v1.z, (f16)v1.w};
  *(f16x8*)(dst + (size_t)gid * 8) = v;
}

// ------------- pass 2: QK^T GEMM + exp-shifted score store ---------------
// 1D grid (npair*16), XCD-clustered: XCD x owns q-tiles [x*npair/8, +npair/8),
// kt-major progression -> Q-tiles stay resident in one L2.
// 128q x 256k tile, 4 waves 2x2 (wy: q-half, wx: 128-key half), BK=32.
// (m_t, l_t) at 128-col granularity -> fully wave-local (no LDS merges).
__global__ __launch_bounds__(256, 2) void k_qk(
    const f16* __restrict__ Qt, const f16* __restrict__ Kt,
    f16* __restrict__ E, float2* __restrict__ mlpart,
    int qspan, int qt128, int npair) {
  int id = blockIdx.x, pair, kt;
  if ((npair & 7) == 0) {
    int xcd = id & 7, j = id >> 3, qrs = npair >> 3;
    pair = xcd * qrs + (j % qrs);
    kt = j / qrs;
  } else {
    pair = id >> 4;
    kt = id & 15;
  }
  int bz = pair / qt128, qt = pair - bz * qt128;

  const f16* Aq = Qt + ((size_t)(bz * qspan + qt * 128)) * C_;
  const f16* Bk = Kt + (size_t)bz * HW_ * C_ + (size_t)kt * 256 * C_;
  f16* Eb = E + ((size_t)(bz * qspan + qt * 128)) * HW_ + kt * 256;
  float2* mlb = mlpart + ((size_t)(bz * qspan + qt * 128)) * 32 + kt * 2;

  // K-loop staging As/Bs; epilogue reuses the LDS as a full 128-row
  // transpose buffer (stride 272 f16).
  __shared__ __align__(16) union ShQK {
    struct { f16 As[128 * 32]; f16 Bs[256 * 32]; } s;
    f16 ebuf[128 * 272];
  } sh;
  f16* As = sh.s.As;
  f16* Bs = sh.s.Bs;

  int t = threadIdx.x, wave = t >> 6, lane = t & 63, lq = lane & 15, quad = lane >> 4;
  int wy = wave >> 1, wx = wave & 1;
  int srow = t >> 2, scol = (t & 3) * 8;

  f32x4 acc[4][8];
#pragma unroll
  for (int mt = 0; mt < 4; ++mt)
#pragma unroll
    for (int nt = 0; nt < 8; ++nt) acc[mt][nt] = (f32x4){0, 0, 0, 0};

  for (int kc = 0; kc < 16; ++kc) {
    __syncthreads();
    g2l16(Aq + (size_t)srow * C_ + kc * 32 + scol, As + t * 8);
    g2l16(Aq + (size_t)(srow + 64) * C_ + kc * 32 + scol, As + 2048 + t * 8);
#pragma unroll
    for (int i = 0; i < 4; ++i)
      g2l16(Bk + (size_t)(srow + 64 * i) * C_ + kc * 32 + scol,
            Bs + i * 2048 + t * 8);
    __syncthreads();
    f16x8 af[4], bf[8];
#pragma unroll
    for (int mt = 0; mt < 4; ++mt)
      af[mt] = *(const f16x8*)(As + (wy * 64 + mt * 16 + lq) * 32 + quad * 8);
#pragma unroll
    for (int nt = 0; nt < 8; ++nt)
      bf[nt] = *(const f16x8*)(Bs + (wx * 128 + nt * 16 + lq) * 32 + quad * 8);
#pragma unroll
    for (int mt = 0; mt < 4; ++mt)
#pragma unroll
      for (int nt = 0; nt < 8; ++nt)
        acc[mt][nt] = mfma16(af[mt], bf[nt], acc[mt][nt]);
  }

  // ---- wave-local row max over this wave's 128 cols ----
  float mrow[4][4], rsum[4][4];
#pragma unroll
  for (int mt = 0; mt < 4; ++mt)
#pragma unroll
    for (int r = 0; r < 4; ++r) {
      float v = -1e30f;
#pragma unroll
      for (int nt = 0; nt < 8; ++nt) v = fmaxf(v, acc[mt][nt][r]);
#pragma unroll
      for (int msk = 1; msk < 16; msk <<= 1) v = fmaxf(v, __shfl_xor(v, msk));
      mrow[mt][r] = v;
      rsum[mt][r] = 0.f;
    }

  __syncthreads();  // all waves done reading As/Bs before ebuf reuse

  // ---- E = exp(s - m_t) into ebuf (single phase), accumulate row sums ----
#pragma unroll
  for (int mt = 0; mt < 4; ++mt)
#pragma unroll
    for (int nt = 0; nt < 8; ++nt) {
      f32x4 v = acc[mt][nt];
#pragma unroll
      for (int r = 0; r < 4; ++r) {
        float e = __expf(v[r] - mrow[mt][r]);
        rsum[mt][r] += e;
        sh.ebuf[(wy * 64 + mt * 16 + quad * 4 + r) * 272 +
                wx * 128 + nt * 16 + lq] = (f16)e;
      }
    }

  // (m_t, l_t) per (row, 128-col half) -> wave-local store (no barrier dep)
#pragma unroll
  for (int mt = 0; mt < 4; ++mt)
#pragma unroll
    for (int r = 0; r < 4; ++r) {
      float v = rsum[mt][r];
#pragma unroll
      for (int msk = 1; msk < 16; msk <<= 1) v += __shfl_xor(v, msk);
      if (lq == 0) {
        int rr = wy * 64 + mt * 16 + quad * 4 + r;
        mlb[(size_t)rr * 32 + wx] = make_float2(mrow[mt][r], v);
      }
    }
  __syncthreads();  // ebuf visible

  // ---- coalesced 16B stores of the whole 128x256 E tile ----
#pragma unroll
  for (int i = 0; i < 16; ++i) {
    int idx = i * 256 + t;
    int rl = idx >> 5, cs = (idx & 31) * 8;
    f16x8 v8 = *(const f16x8*)(sh.ebuf + rl * 272 + cs);
    *(f16x8*)(Eb + (size_t)rl * HW_ + cs) = v8;
  }
}

// ---- pass 3: exact softmax merge -> alpha[row][kt32] = exp(m_t-m)/l ------
__global__ __launch_bounds__(256) void k_red(const float2* __restrict__ mlpart,
                                             float* __restrict__ alpha) {
  int row = blockIdx.x * 256 + threadIdx.x;
  const float2* p = mlpart + (size_t)row * 32;
  float2 loc[32];
  float m = -1e30f;
#pragma unroll
  for (int i = 0; i < 32; ++i) {
    loc[i] = p[i];
    m = fmaxf(m, loc[i].x);
  }
  float l = 0.f;
#pragma unroll
  for (int i = 0; i < 32; ++i) l += loc[i].y * __expf(loc[i].x - m);
  float invl = 1.f / l;
#pragma unroll
  for (int i = 0; i < 32; ++i)
    alpha[(size_t)row * 32 + i] = __expf(loc[i].x - m) * invl;
}

// ------ pass 4: (E*alpha) x V GEMM, V^2 in-register + fused epilogue ------
// 1D grid, XCD-clustered: each XCD owns npairs/8 q-tiles x all 4 ct tiles
// so a P-tile is fetched into ONE L2 and hit by its 4 ct-blocks.
// 128q x 128ch tile, two accumulator planes (M from V, M2 from V*V in-reg).
// 4 waves 2x2 (wy: q-half, wx: 64-ch half).
__global__ __launch_bounds__(256, 2) void k_pv(
    const f16* __restrict__ P, const float* __restrict__ alphaG,
    const f16* __restrict__ V, const float* __restrict__ cx,
    const float2* __restrict__ cxs, float* __restrict__ out,
    int qspan, int qbase, int qt128) {
  int npairs = (int)gridDim.x >> 2;
  int id = blockIdx.x, pair, ct;
  if ((npairs & 7) == 0) {
    int x = id & 7, j = id >> 3, ppx = npairs >> 3;
    pair = x * ppx + (j >> 2);
    ct = j & 3;
  } else {
    pair = id >> 2;
    ct = id & 3;
  }
  int bz = pair / qt128, qt = pair - bz * qt128;

  const f16* Ap = P + ((size_t)(bz * qspan + qt * 128)) * HW_;
  const f16* Bv = V + ((size_t)(bz * C_ + ct * 128)) * HW_;

  __shared__ __align__(16) f16 As[128 * 32], Bs[128 * 32];
  __shared__ float Al[128 * 33];  // alpha, stride 33 (coprime 32): conflict-free

  int t = threadIdx.x, wave = t >> 6, lane = t & 63, lq = lane & 15, quad = lane >> 4;
  int wy = wave >> 1, wx = wave & 1;
  int srow = t >> 2, scol = (t & 3) * 8;

  // stage alpha for this block's 128 rows x 32 kt (coalesced f32 loads)
  {
    const float* ag = alphaG + ((size_t)(bz * qspan + qt * 128)) * 32;
#pragma unroll
    for (int i = 0; i < 16; ++i) {
      int e = i * 256 + t;
      Al[(e >> 5) * 33 + (e & 31)] = ag[e];
    }
  }

  f32x4 accM[4][4], accM2[4][4];
#pragma unroll
  for (int mt = 0; mt < 4; ++mt)
#pragma unroll
    for (int nt = 0; nt < 4; ++nt) {
      accM[mt][nt] = (f32x4){0, 0, 0, 0};
      accM2[mt][nt] = (f32x4){0, 0, 0, 0};
    }

  for (int kc = 0; kc < 128; ++kc) {
    __syncthreads();  // prev iter LDS reads done (also covers alpha stage @kc=0)
    g2l16(Ap + (size_t)srow * HW_ + kc * 32 + scol, As + t * 8);
    g2l16(Ap + (size_t)(srow + 64) * HW_ + kc * 32 + scol, As + 2048 + t * 8);
    g2l16(Bv + (size_t)srow * HW_ + kc * 32 + scol, Bs + t * 8);
    g2l16(Bv + (size_t)(srow + 64) * HW_ + kc * 32 + scol, Bs + 2048 + t * 8);
    __syncthreads();  // staging visible

    int ktl = kc >> 2;  // 128-key alpha tiles
    f16x8 af[4], bf[4], bf2[4];
#pragma unroll
    for (int mt = 0; mt < 4; ++mt) {
      af[mt] = *(const f16x8*)(As + (wy * 64 + mt * 16 + lq) * 32 + quad * 8);
      f16 a = (f16)Al[(wy * 64 + mt * 16 + lq) * 33 + ktl];
      af[mt] = af[mt] * a;  // fold softmax alpha into A-fragment
    }
#pragma unroll
    for (int nt = 0; nt < 4; ++nt) {
      bf[nt] = *(const f16x8*)(Bs + (wx * 64 + nt * 16 + lq) * 32 + quad * 8);
      bf2[nt] = bf[nt] * bf[nt];  // V^2 in-register
    }
#pragma unroll
    for (int mt = 0; mt < 4; ++mt)
#pragma unroll
      for (int nt = 0; nt < 4; ++nt) {
        accM[mt][nt] = mfma16(af[mt], bf[nt], accM[mt][nt]);
        accM2[mt][nt] = mfma16(af[mt], bf2[nt], accM2[mt][nt]);
      }
  }

  // epilogue: all lanes active; lane lq = channel, rows q0..q0+3
  int chbase = ct * 128 + wx * 64;
#pragma unroll
  for (int mt = 0; mt < 4; ++mt) {
    int q0 = qbase + qt * 128 + wy * 64 + mt * 16 + quad * 4;
#pragma unroll
    for (int nt = 0; nt < 4; ++nt) {
      int c = chbase + nt * 16 + lq;
      float2 st = cxs[bz * C_ + c];
      size_t base = ((size_t)bz * C_ + c) * HW_ + q0;
      float4 cv = *(const float4*)(cx + base);
      f32x4 m1 = accM[mt][nt], m2 = accM2[mt][nt];
      float4 o;
      o.x = sqrtf(fmaxf(m2[0] - m1[0] * m1[0], 1e-6f)) * ((cv.x - st.x) * st.y) + m1[0];
      o.y = sqrtf(fmaxf(m2[1] - m1[1] * m1[1], 1e-6f)) * ((cv.y - st.x) * st.y) + m1[1];
      o.z = sqrtf(fmaxf(m2[2] - m1[2] * m1[2], 1e-6f)) * ((cv.z - st.x) * st.y) + m1[2];
      o.w = sqrtf(fmaxf(m2[3] - m1[3] * m1[3], 1e-6f)) * ((cv.w - st.x) * st.y) + m1[3];
      *(float4*)(out + base) = o;
    }
  }
}

// --------------------------------- host -----------------------------------
extern "C" void kernel_launch(void* const* d_in, const int* in_sizes, int n_in,
                              void* d_out, int out_size, void* d_ws,
                              size_t ws_size, hipStream_t stream) {
  const float* c_x = (const float*)d_in[0];
  const float* s_x = (const float*)d_in[1];
  const float* c1x = (const float*)d_in[2];
  const float* s1x = (const float*)d_in[3];
  float* out = (float*)d_out;

  char* ws = (char*)d_ws;
  size_t o = 0;
  f16* Qt = (f16*)(ws + o);  o += (size_t)B_ * HW_ * C_ * 2;        // 16 MiB
  f16* Kt = (f16*)(ws + o);  o += (size_t)B_ * HW_ * C_ * 2;        // 16 MiB
  f16* Vh = (f16*)(ws + o);  o += (size_t)B_ * HW_ * C_ * 2;        // 16 MiB
  float2* cxs = (float2*)(ws + o); o += B_ * C_ * sizeof(float2);
  float2* c1s = (float2*)(ws + o); o += B_ * C_ * sizeof(float2);
  float2* s1s = (float2*)(ws + o); o += B_ * C_ * sizeof(float2);
  size_t fixed = (o + 255) & ~(size_t)255;

  // score-region tiers: rows = nb*qspan; bytes/row = E + mlpart + alpha(f32)
  const size_t per_row = (size_t)HW_ * 2 + 32 * 8 + 32 * 4;
  struct Cfg { int nb, qs; };
  const Cfg cfgs[5] = {{4, 4096}, {1, 4096}, {1, 2048}, {1, 1024}, {1, 512}};
  Cfg cfg = cfgs[4];
  for (int i = 0; i < 5; ++i) {
    size_t rows = (size_t)cfgs[i].nb * cfgs[i].qs;
    if (fixed + rows * per_row <= ws_size) { cfg = cfgs[i]; break; }
  }
  const int nb = cfg.nb, qspan = cfg.qs, qt128 = qspan / 128;
  const int npair = nb * qt128;
  const size_t rows = (size_t)nb * qspan;
  f16* E = (f16*)(ws + fixed);
  float2* mlpart = (float2*)(ws + fixed + rows * HW_ * 2);
  float* alpha = (float*)(ws + fixed + rows * HW_ * 2 + rows * 32 * 8);

  k_stats<<<dim3(C_ / 4, B_, 3), 256, 0, stream>>>(c_x, c1x, s1x, cxs, c1s, s1s);
  k_prept<<<dim3(HW_ / 64, C_ / 64, 2 * B_), 256, 0, stream>>>(c1x, s1x, c1s,
                                                               s1s, Qt, Kt);
  k_prepv<<<dim3(B_ * C_ * HW_ / 8 / 256), 256, 0, stream>>>(s_x, Vh);

  for (int b0 = 0; b0 < B_; b0 += nb) {
    for (int qb = 0; qb < HW_; qb += qspan) {
      const f16* Qtp = Qt + ((size_t)b0 * HW_ + qb) * C_;
      const f16* Ktp = Kt + (size_t)b0 * HW_ * C_;
      const f16* Vp = Vh + (size_t)b0 * C_ * HW_;
      const float* cxp = c_x + (size_t)b0 * C_ * HW_;
      const float2* cxsp = cxs + b0 * C_;
      float* outp = out + (size_t)b0 * C_ * HW_;

      k_qk<<<dim3((unsigned)(npair * 16)), 256, 0, stream>>>(
          Qtp, Ktp, E, mlpart, qspan, qt128, npair);
      k_red<<<dim3((unsigned)(rows / 256)), 256, 0, stream>>>(mlpart, alpha);
      k_pv<<<dim3((unsigned)(npair * 4)), 256, 0, stream>>>(
          E, alpha, Vp, cxp, cxsp, outp, qspan, qb, qt128);
    }
  }
}